// Round 6
// baseline (383.458 us; speedup 1.0000x reference)
//
#include <hip/hip_runtime.h>
#include <math.h>

#define NN 50000
#define NE 600000
#define ET (NE + NN)        // 650000 edges incl self loops
#define D 128
#define EPSB 1e-5f
#define SLOPE 0.2f
#define XPITCH 136          // LDS row pitch in bf16 elems (128 + 8 pad)
#define SCB 196             // scan blocks: 196*256 = 50176 >= NN

typedef float f32x4 __attribute__((ext_vector_type(4)));
typedef short bf16x8 __attribute__((ext_vector_type(8)));

__device__ inline unsigned short bf16r(float f) {           // f32 -> bf16 RNE
    unsigned int u = __float_as_uint(f);
    unsigned int r = (u + 0x7fff + ((u >> 16) & 1)) >> 16;
    return (unsigned short)r;
}
__device__ inline float bflo(unsigned int u) { return __uint_as_float(u << 16); }
__device__ inline float bfhi(unsigned int u) { return __uint_as_float(u & 0xffff0000u); }
__device__ inline float lrelu(float e) { return (e > 0.f) ? e : SLOPE * e; }

// ---------------- CSR build ----------------
__global__ void hist_kernel(const int* __restrict__ ei, int* __restrict__ deg) {
    int e = blockIdx.x * blockDim.x + threadIdx.x;
    if (e >= ET) return;
    int dst = (e < NE) ? ei[NE + e] : (e - NE);
    atomicAdd(&deg[dst], 1);
}

__global__ __launch_bounds__(256) void scan_a_kernel(const int* __restrict__ deg,
                                                     int* __restrict__ tmp,
                                                     int* __restrict__ bsum) {
    __shared__ int sm[256];
    int t = threadIdx.x;
    int idx = blockIdx.x * 256 + t;
    int v = (idx < NN) ? deg[idx] : 0;
    sm[t] = v;
    __syncthreads();
    #pragma unroll
    for (int d = 1; d < 256; d <<= 1) {
        int add = (t >= d) ? sm[t - d] : 0;
        __syncthreads();
        sm[t] += add;
        __syncthreads();
    }
    if (idx < NN) tmp[idx] = sm[t];
    if (t == 255) bsum[blockIdx.x] = sm[255];
}

__global__ __launch_bounds__(256) void scan_b_kernel(const int* __restrict__ deg,
                                                     const int* __restrict__ tmp,
                                                     const int* __restrict__ bsum,
                                                     int* __restrict__ offs,
                                                     int* __restrict__ cur) {
    __shared__ int sm[256];
    int t = threadIdx.x;
    sm[t] = (t < SCB) ? bsum[t] : 0;
    __syncthreads();
    #pragma unroll
    for (int d = 1; d < 256; d <<= 1) {
        int add = (t >= d) ? sm[t - d] : 0;
        __syncthreads();
        sm[t] += add;
        __syncthreads();
    }
    int bpre = (blockIdx.x == 0) ? 0 : sm[blockIdx.x - 1];
    int idx = blockIdx.x * 256 + t;
    if (idx < NN) {
        int excl = bpre + tmp[idx] - deg[idx];
        offs[idx] = excl;
        cur[idx] = excl;
        if (idx == NN - 1) offs[NN] = bpre + tmp[idx];   // == ET
    }
}

__global__ void scatter_kernel(const int* __restrict__ ei, int* __restrict__ cur,
                               int* __restrict__ ssrc, int* __restrict__ sdst) {
    int e = blockIdx.x * blockDim.x + threadIdx.x;
    if (e >= ET) return;
    int src, dst;
    if (e < NE) { src = ei[e]; dst = ei[NE + e]; }
    else        { src = dst = e - NE; }
    int pos = atomicAdd(&cur[dst], 1);
    ssrc[pos] = src;
    sdst[pos] = dst;
}

// ---------------- both W -> bf16 transposed ----------------
__global__ void wconv_kernel(const float* __restrict__ W1, const float* __restrict__ W2,
                             unsigned short* __restrict__ wt1, unsigned short* __restrict__ wt2) {
    int t = blockIdx.x * blockDim.x + threadIdx.x;
    if (t >= 2 * D * D) return;
    int i = (t < D * D) ? t : t - D * D;
    int n = i >> 7, k = i & 127;
    if (t < D * D) wt1[i] = bf16r(W1[k * D + n]);
    else           wt2[i] = bf16r(W2[k * D + n]);
}

// ---------------- MFMA GEMM: Hb(bf16) = f(X) @ W ; f = BN+ReLU if BNRELU ----------------
template <bool BNRELU>
__global__ __launch_bounds__(256) void gemm_mfma_kernel(const float* __restrict__ X,
                                                        const unsigned short* __restrict__ Wt,
                                                        const float* __restrict__ scsh,
                                                        unsigned short* __restrict__ Hb, int nrows) {
    __shared__ unsigned short Xl[64 * XPITCH];
    __shared__ unsigned short Wl[128 * XPITCH];
    int t = threadIdx.x;
    int row0 = blockIdx.x * 64;

    {
        int r = t >> 1, cb = (t & 1) * 64;
        const uint4* src = (const uint4*)&Wt[r * D + cb];
        uint4* dst = (uint4*)&Wl[r * XPITCH + cb];
        #pragma unroll
        for (int j = 0; j < 8; ++j) dst[j] = src[j];
    }
    {
        int r = t >> 2, cb = (t & 3) * 32;
        int gr = row0 + r; if (gr >= nrows) gr = nrows - 1;
        const float4* src = (const float4*)&X[(long)gr * D + cb];
        #pragma unroll
        for (int j = 0; j < 8; ++j) {
            float4 v = src[j];
            if (BNRELU) {
                float4 g = *(const float4*)&scsh[cb + j * 4];
                float4 s = *(const float4*)&scsh[D + cb + j * 4];
                v.x = fmaxf(fmaf(v.x, g.x, s.x), 0.f);
                v.y = fmaxf(fmaf(v.y, g.y, s.y), 0.f);
                v.z = fmaxf(fmaf(v.z, g.z, s.z), 0.f);
                v.w = fmaxf(fmaf(v.w, g.w, s.w), 0.f);
            }
            ushort4 p;
            p.x = bf16r(v.x); p.y = bf16r(v.y);
            p.z = bf16r(v.z); p.w = bf16r(v.w);
            *(ushort4*)&Xl[r * XPITCH + cb + j * 4] = p;
        }
    }
    __syncthreads();

    int wv = t >> 6, l = t & 63;
    int lr = l & 15, lg = l >> 4;
    f32x4 acc[8];
    #pragma unroll
    for (int n = 0; n < 8; ++n) acc[n] = (f32x4){0.f, 0.f, 0.f, 0.f};

    #pragma unroll
    for (int kc = 0; kc < 4; ++kc) {
        bf16x8 a = *(const bf16x8*)&Xl[(wv * 16 + lr) * XPITCH + kc * 32 + lg * 8];
        #pragma unroll
        for (int n = 0; n < 8; ++n) {
            bf16x8 b = *(const bf16x8*)&Wl[(n * 16 + lr) * XPITCH + kc * 32 + lg * 8];
            acc[n] = __builtin_amdgcn_mfma_f32_16x16x32_bf16(a, b, acc[n], 0, 0, 0);
        }
    }
    int growb = row0 + wv * 16 + lg * 4;
    #pragma unroll
    for (int n = 0; n < 8; ++n) {
        #pragma unroll
        for (int j = 0; j < 4; ++j) {
            int gr = growb + j;
            if (gr < nrows) Hb[(long)gr * D + n * 16 + lr] = bf16r(acc[n][j]);
        }
    }
}

// ---------------- per-node logits (bf16 H) ----------------
template <int H>
__global__ void logits_kernel(const unsigned short* __restrict__ Hb,
                              const float* __restrict__ a_src,
                              const float* __restrict__ a_dst,
                              float* __restrict__ es, float* __restrict__ ed) {
    int i = blockIdx.x * blockDim.x + threadIdx.x;
    if (i >= NN * H) return;
    int n = i / H, h = i % H;
    const int CH = D / H;
    const unsigned short* hp = Hb + (long)n * D + h * CH;
    const float* as = a_src + h * CH;
    const float* ad = a_dst + h * CH;
    float s = 0.f, d = 0.f;
    for (int c = 0; c < CH; c += 8) {
        uint4 u = *(const uint4*)&hp[c];
        float4 a0 = *(const float4*)&as[c];
        float4 a1 = *(const float4*)&as[c + 4];
        float4 b0 = *(const float4*)&ad[c];
        float4 b1 = *(const float4*)&ad[c + 4];
        float f0 = bflo(u.x), f1 = bfhi(u.x), f2 = bflo(u.y), f3 = bfhi(u.y);
        float f4 = bflo(u.z), f5 = bfhi(u.z), f6 = bflo(u.w), f7 = bfhi(u.w);
        s += f0 * a0.x + f1 * a0.y + f2 * a0.z + f3 * a0.w
           + f4 * a1.x + f5 * a1.y + f6 * a1.z + f7 * a1.w;
        d += f0 * b0.x + f1 * b0.y + f2 * b0.z + f3 * b0.w
           + f4 * b1.x + f5 * b1.y + f6 * b1.z + f7 * b1.w;
    }
    es[i] = s; ed[i] = d;
}

// ---------------- per-edge softmax numerators (CSR order) ----------------
template <int H>
__global__ void ew_kernel(const int* __restrict__ ssrc, const int* __restrict__ sdst,
                          const float* __restrict__ es, const float* __restrict__ ed,
                          float* __restrict__ wext) {
    int i = blockIdx.x * blockDim.x + threadIdx.x;
    if (i >= ET) return;
    int s = ssrc[i], dd = sdst[i];
    if (H == 4) {
        float4 a = *(const float4*)&es[s * 4];
        float4 b = *(const float4*)&ed[dd * 4];
        float4 w;
        w.x = __expf(lrelu(a.x + b.x));
        w.y = __expf(lrelu(a.y + b.y));
        w.z = __expf(lrelu(a.z + b.z));
        w.w = __expf(lrelu(a.w + b.w));
        *(float4*)&wext[i * 4] = w;
    } else {
        wext[i] = __expf(lrelu(es[s] + ed[dd]));
    }
}

// ---------------- aggregation: one wave per dst, pure gather+FMA ----------------
// RECON: residual recomputed as relu(g*resid + s) from scsh (layer 2)
template <int H, bool RECON>
__global__ __launch_bounds__(256) void agg_kernel(const unsigned short* __restrict__ Hb,
                                                  const float* __restrict__ wext,
                                                  const int* __restrict__ offs,
                                                  const int* __restrict__ ssrc,
                                                  const float* __restrict__ bias,
                                                  const float* __restrict__ resid,
                                                  const float* __restrict__ scsh,
                                                  float* __restrict__ out) {
    int wave = threadIdx.x >> 6;
    int lane = threadIdx.x & 63;
    int dst = blockIdx.x * 4 + wave;
    if (dst >= NN) return;
    int h = (H == 1) ? 0 : (lane >> 4);
    int fo = lane * 2;
    int beg = offs[dst], end = offs[dst + 1];
    float2 a0 = {0.f,0.f}, a1 = {0.f,0.f}, a2 = {0.f,0.f}, a3 = {0.f,0.f};
    float d0 = 0.f, d1 = 0.f, d2 = 0.f, d3 = 0.f;
    int idx = beg;
    for (; idx + 3 < end; idx += 4) {
        int s0 = ssrc[idx], s1 = ssrc[idx+1], s2 = ssrc[idx+2], s3 = ssrc[idx+3];
        float w0 = wext[(idx)   * H + h];
        float w1 = wext[(idx+1) * H + h];
        float w2 = wext[(idx+2) * H + h];
        float w3 = wext[(idx+3) * H + h];
        unsigned int u0 = *(const unsigned int*)&Hb[(long)s0 * D + fo];
        unsigned int u1 = *(const unsigned int*)&Hb[(long)s1 * D + fo];
        unsigned int u2 = *(const unsigned int*)&Hb[(long)s2 * D + fo];
        unsigned int u3 = *(const unsigned int*)&Hb[(long)s3 * D + fo];
        a0.x += w0 * bflo(u0); a0.y += w0 * bfhi(u0); d0 += w0;
        a1.x += w1 * bflo(u1); a1.y += w1 * bfhi(u1); d1 += w1;
        a2.x += w2 * bflo(u2); a2.y += w2 * bfhi(u2); d2 += w2;
        a3.x += w3 * bflo(u3); a3.y += w3 * bfhi(u3); d3 += w3;
    }
    for (; idx < end; ++idx) {
        int s0 = ssrc[idx];
        float w0 = wext[idx * H + h];
        unsigned int u0 = *(const unsigned int*)&Hb[(long)s0 * D + fo];
        a0.x += w0 * bflo(u0); a0.y += w0 * bfhi(u0); d0 += w0;
    }
    float dsum = (d0 + d1) + (d2 + d3);
    float accx = (a0.x + a1.x) + (a2.x + a3.x);
    float accy = (a0.y + a1.y) + (a2.y + a3.y);
    float inv = 1.0f / dsum;
    float2 rr = *(const float2*)&resid[(long)dst * D + fo];
    if (RECON) {
        float2 g = *(const float2*)&scsh[fo];
        float2 s = *(const float2*)&scsh[D + fo];
        rr.x = fmaxf(fmaf(rr.x, g.x, s.x), 0.f);
        rr.y = fmaxf(fmaf(rr.y, g.y, s.y), 0.f);
    }
    float2 o;
    o.x = accx * inv + bias[fo]     + rr.x;
    o.y = accy * inv + bias[fo + 1] + rr.y;
    *(float2*)&out[(long)dst * D + fo] = o;
}

// ---------------- batch-norm stats / finalize / fused apply ----------------
__global__ __launch_bounds__(128) void stats_kernel(const float* __restrict__ y,
                                                    float* __restrict__ st) {
    int f = threadIdx.x;
    float s = 0.f, q = 0.f;
    for (int r = blockIdx.x; r < NN; r += gridDim.x) {
        float v = y[(long)r * D + f];
        s += v; q += v * v;
    }
    atomicAdd(&st[f], s);
    atomicAdd(&st[D + f], q);
}

__global__ void finalize_kernel(const float* __restrict__ st,
                                const float* __restrict__ gamma,
                                const float* __restrict__ beta,
                                float* __restrict__ scsh) {
    int f = threadIdx.x;
    if (f >= D) return;
    float mean = st[f] * (1.0f / NN);
    float var = st[D + f] * (1.0f / NN) - mean * mean;
    float g = gamma[f] * rsqrtf(var + EPSB);
    scsh[f] = g;
    scsh[D + f] = beta[f] - mean * g;
}

template <bool RELU>
__global__ __launch_bounds__(256) void apply_kernel(const float* __restrict__ y,
                                                    const float* __restrict__ st,
                                                    const float* __restrict__ gamma,
                                                    const float* __restrict__ beta,
                                                    float* __restrict__ out) {
    long i = (long)(blockIdx.x * blockDim.x + threadIdx.x) * 4;
    if (i >= (long)NN * D) return;
    int f = (int)(i & (D - 1));
    const float invn = 1.0f / NN;
    float4 sv = *(const float4*)&st[f];
    float4 qv = *(const float4*)&st[D + f];
    float4 gv = *(const float4*)&gamma[f];
    float4 bv = *(const float4*)&beta[f];
    float4 v = *(const float4*)&y[i];
    float4 o;
    float m, vr, g;
    m = sv.x * invn; vr = qv.x * invn - m * m; g = gv.x * rsqrtf(vr + EPSB);
    o.x = (v.x - m) * g + bv.x;
    m = sv.y * invn; vr = qv.y * invn - m * m; g = gv.y * rsqrtf(vr + EPSB);
    o.y = (v.y - m) * g + bv.y;
    m = sv.z * invn; vr = qv.z * invn - m * m; g = gv.z * rsqrtf(vr + EPSB);
    o.z = (v.z - m) * g + bv.z;
    m = sv.w * invn; vr = qv.w * invn - m * m; g = gv.w * rsqrtf(vr + EPSB);
    o.w = (v.w - m) * g + bv.w;
    if (RELU) {
        o.x = fmaxf(o.x, 0.f); o.y = fmaxf(o.y, 0.f);
        o.z = fmaxf(o.z, 0.f); o.w = fmaxf(o.w, 0.f);
    }
    *(float4*)&out[i] = o;
}

extern "C" void kernel_launch(void* const* d_in, const int* in_sizes, int n_in,
                              void* d_out, int out_size, void* d_ws, size_t ws_size,
                              hipStream_t stream) {
    const float* x      = (const float*)d_in[0];
    const int*   ei     = (const int*)  d_in[1];
    const float* W1     = (const float*)d_in[2];
    const float* a_src1 = (const float*)d_in[3];
    const float* a_dst1 = (const float*)d_in[4];
    const float* b1     = (const float*)d_in[5];
    const float* W2     = (const float*)d_in[6];
    const float* a_src2 = (const float*)d_in[7];
    const float* a_dst2 = (const float*)d_in[8];
    const float* b2     = (const float*)d_in[9];
    const float* gamma  = (const float*)d_in[10];
    const float* beta   = (const float*)d_in[11];
    float* out = (float*)d_out;

    // workspace layout
    unsigned short* Hb = (unsigned short*)d_ws;          // 6.4M bf16 (12.8 MB)
    float* B    = (float*)d_ws + 3200000;                // y1 = h1+res (pre-BN)
    float* es1  = B + 6400000;                           // 200000 ([NN][4])
    float* ed1  = es1 + 200000;
    float* es2  = ed1 + 200000;                          // 50000
    float* ed2  = es2 + 50000;
    float* st1  = ed2 + 50000;                           // 256
    float* st2  = st1 + 256;
    float* scsh1= st2 + 256;                             // 256
    float* wext = scsh1 + 256;                           // ET*4 floats (layer1), reused (ET) layer2
    int*   deg  = (int*)(wext + ET * 4);                 // NN
    int*   offs = deg + NN;                              // NN+1
    int*   cur  = offs + NN + 1;                         // NN
    int*   ssrc = cur + NN;                              // ET
    int*   sdst = ssrc + ET;                             // ET
    int*   tmp  = sdst + ET;                             // NN
    int*   bsum = tmp + NN;                              // SCB
    unsigned short* wt1 = (unsigned short*)(bsum + SCB + 4);
    unsigned short* wt2 = wt1 + D * D;

    hipMemsetAsync(deg, 0, NN * sizeof(int), stream);
    hipMemsetAsync(st1, 0, 512 * sizeof(float), stream);

    wconv_kernel<<<(2 * D * D + 255) / 256, 256, 0, stream>>>(W1, W2, wt1, wt2);
    hist_kernel<<<(ET + 255) / 256, 256, 0, stream>>>(ei, deg);
    scan_a_kernel<<<SCB, 256, 0, stream>>>(deg, tmp, bsum);
    scan_b_kernel<<<SCB, 256, 0, stream>>>(deg, tmp, bsum, offs, cur);
    scatter_kernel<<<(ET + 255) / 256, 256, 0, stream>>>(ei, cur, ssrc, sdst);

    const int GG = (NN + 63) / 64;
    const int EB = (ET + 255) / 256;
    // ---- layer 1 ----
    gemm_mfma_kernel<false><<<GG, 256, 0, stream>>>(x, wt1, nullptr, Hb, NN);
    logits_kernel<4><<<(NN * 4 + 255) / 256, 256, 0, stream>>>(Hb, a_src1, a_dst1, es1, ed1);
    ew_kernel<4><<<EB, 256, 0, stream>>>(ssrc, sdst, es1, ed1, wext);
    agg_kernel<4, false><<<(NN + 3) / 4, 256, 0, stream>>>(Hb, wext, offs, ssrc, b1, x, nullptr, B);
    stats_kernel<<<1024, 128, 0, stream>>>(B, st1);
    finalize_kernel<<<1, 128, 0, stream>>>(st1, gamma, beta, scsh1);

    // ---- layer 2 (BN+ReLU of layer1 fused into staging / residual recompute) ----
    gemm_mfma_kernel<true><<<GG, 256, 0, stream>>>(B, wt2, scsh1, Hb, NN);
    logits_kernel<1><<<(NN + 255) / 256, 256, 0, stream>>>(Hb, a_src2, a_dst2, es2, ed2);
    ew_kernel<1><<<EB, 256, 0, stream>>>(ssrc, sdst, es2, ed2, wext);
    agg_kernel<1, true><<<(NN + 3) / 4, 256, 0, stream>>>(Hb, wext, offs, ssrc, b2, B, scsh1, out);
    stats_kernel<<<1024, 128, 0, stream>>>(out, st2);
    apply_kernel<false><<<(NN * D / 4 + 255) / 256, 256, 0, stream>>>(out, st2, gamma, beta, out);
}

// Round 10
// 369.804 us; speedup vs baseline: 1.0369x; 1.0369x over previous
//
#include <hip/hip_runtime.h>
#include <math.h>

#define NN 50000
#define NE 600000
#define ET (NE + NN)        // 650000 edges incl self loops
#define D 128
#define EPSB 1e-5f
#define SLOPE 0.2f
#define XPITCH 136          // LDS row pitch in bf16 elems (128 + 8 pad)
#define SCB 196             // scan blocks: 196*256 = 50176 >= NN

typedef float f32x4 __attribute__((ext_vector_type(4)));
typedef short bf16x8 __attribute__((ext_vector_type(8)));

__device__ inline unsigned short bf16r(float f) {           // f32 -> bf16 RNE
    unsigned int u = __float_as_uint(f);
    unsigned int r = (u + 0x7fff + ((u >> 16) & 1)) >> 16;
    return (unsigned short)r;
}
__device__ inline float bflo(unsigned int u) { return __uint_as_float(u << 16); }
__device__ inline float bfhi(unsigned int u) { return __uint_as_float(u & 0xffff0000u); }
__device__ inline float lrelu(float e) { return (e > 0.f) ? e : SLOPE * e; }

// ---------------- CSR build ----------------
__global__ void hist_kernel(const int* __restrict__ ei, int* __restrict__ deg) {
    int e = blockIdx.x * blockDim.x + threadIdx.x;
    if (e >= ET) return;
    int dst = (e < NE) ? ei[NE + e] : (e - NE);
    atomicAdd(&deg[dst], 1);
}

__global__ __launch_bounds__(256) void scan_a_kernel(const int* __restrict__ deg,
                                                     int* __restrict__ tmp,
                                                     int* __restrict__ bsum) {
    __shared__ int sm[256];
    int t = threadIdx.x;
    int idx = blockIdx.x * 256 + t;
    int v = (idx < NN) ? deg[idx] : 0;
    sm[t] = v;
    __syncthreads();
    #pragma unroll
    for (int d = 1; d < 256; d <<= 1) {
        int add = (t >= d) ? sm[t - d] : 0;
        __syncthreads();
        sm[t] += add;
        __syncthreads();
    }
    if (idx < NN) tmp[idx] = sm[t];
    if (t == 255) bsum[blockIdx.x] = sm[255];
}

__global__ __launch_bounds__(256) void scan_b_kernel(const int* __restrict__ deg,
                                                     const int* __restrict__ tmp,
                                                     const int* __restrict__ bsum,
                                                     int* __restrict__ offs,
                                                     int* __restrict__ cur) {
    __shared__ int sm[256];
    int t = threadIdx.x;
    sm[t] = (t < SCB) ? bsum[t] : 0;
    __syncthreads();
    #pragma unroll
    for (int d = 1; d < 256; d <<= 1) {
        int add = (t >= d) ? sm[t - d] : 0;
        __syncthreads();
        sm[t] += add;
        __syncthreads();
    }
    int bpre = (blockIdx.x == 0) ? 0 : sm[blockIdx.x - 1];
    int idx = blockIdx.x * 256 + t;
    if (idx < NN) {
        int excl = bpre + tmp[idx] - deg[idx];
        offs[idx] = excl;
        cur[idx] = excl;
        if (idx == NN - 1) offs[NN] = bpre + tmp[idx];   // == ET
    }
}

__global__ void scatter_kernel(const int* __restrict__ ei, int* __restrict__ cur,
                               unsigned short* __restrict__ ssrc) {
    int e = blockIdx.x * blockDim.x + threadIdx.x;
    if (e >= ET) return;
    int src, dst;
    if (e < NE) { src = ei[e]; dst = ei[NE + e]; }
    else        { src = dst = e - NE; }
    int pos = atomicAdd(&cur[dst], 1);
    ssrc[pos] = (unsigned short)src;
}

// ---------------- both W -> bf16 transposed ----------------
__global__ void wconv_kernel(const float* __restrict__ W1, const float* __restrict__ W2,
                             unsigned short* __restrict__ wt1, unsigned short* __restrict__ wt2) {
    int t = blockIdx.x * blockDim.x + threadIdx.x;
    if (t >= 2 * D * D) return;
    int i = (t < D * D) ? t : t - D * D;
    int n = i >> 7, k = i & 127;
    if (t < D * D) wt1[i] = bf16r(W1[k * D + n]);
    else           wt2[i] = bf16r(W2[k * D + n]);
}

// ---------------- MFMA GEMM: Hb(bf16) = f(X) @ W ; f = BN+ReLU if BNRELU ----------------
template <bool BNRELU>
__global__ __launch_bounds__(256) void gemm_mfma_kernel(const float* __restrict__ X,
                                                        const unsigned short* __restrict__ Wt,
                                                        const float* __restrict__ scsh,
                                                        unsigned short* __restrict__ Hb, int nrows) {
    __shared__ unsigned short Xl[64 * XPITCH];
    __shared__ unsigned short Wl[128 * XPITCH];
    int t = threadIdx.x;
    int row0 = blockIdx.x * 64;

    {
        int r = t >> 1, cb = (t & 1) * 64;
        const uint4* src = (const uint4*)&Wt[r * D + cb];
        uint4* dst = (uint4*)&Wl[r * XPITCH + cb];
        #pragma unroll
        for (int j = 0; j < 8; ++j) dst[j] = src[j];
    }
    {
        int r = t >> 2, cb = (t & 3) * 32;
        int gr = row0 + r; if (gr >= nrows) gr = nrows - 1;
        const float4* src = (const float4*)&X[(long)gr * D + cb];
        #pragma unroll
        for (int j = 0; j < 8; ++j) {
            float4 v = src[j];
            if (BNRELU) {
                float4 g = *(const float4*)&scsh[cb + j * 4];
                float4 s = *(const float4*)&scsh[D + cb + j * 4];
                v.x = fmaxf(fmaf(v.x, g.x, s.x), 0.f);
                v.y = fmaxf(fmaf(v.y, g.y, s.y), 0.f);
                v.z = fmaxf(fmaf(v.z, g.z, s.z), 0.f);
                v.w = fmaxf(fmaf(v.w, g.w, s.w), 0.f);
            }
            ushort4 p;
            p.x = bf16r(v.x); p.y = bf16r(v.y);
            p.z = bf16r(v.z); p.w = bf16r(v.w);
            *(ushort4*)&Xl[r * XPITCH + cb + j * 4] = p;
        }
    }
    __syncthreads();

    int wv = t >> 6, l = t & 63;
    int lr = l & 15, lg = l >> 4;
    f32x4 acc[8];
    #pragma unroll
    for (int n = 0; n < 8; ++n) acc[n] = (f32x4){0.f, 0.f, 0.f, 0.f};

    #pragma unroll
    for (int kc = 0; kc < 4; ++kc) {
        bf16x8 a = *(const bf16x8*)&Xl[(wv * 16 + lr) * XPITCH + kc * 32 + lg * 8];
        #pragma unroll
        for (int n = 0; n < 8; ++n) {
            bf16x8 b = *(const bf16x8*)&Wl[(n * 16 + lr) * XPITCH + kc * 32 + lg * 8];
            acc[n] = __builtin_amdgcn_mfma_f32_16x16x32_bf16(a, b, acc[n], 0, 0, 0);
        }
    }
    int growb = row0 + wv * 16 + lg * 4;
    #pragma unroll
    for (int n = 0; n < 8; ++n) {
        #pragma unroll
        for (int j = 0; j < 4; ++j) {
            int gr = growb + j;
            if (gr < nrows) Hb[(long)gr * D + n * 16 + lr] = bf16r(acc[n][j]);
        }
    }
}

// ---------------- per-node logits (bf16 H) ----------------
template <int H>
__global__ void logits_kernel(const unsigned short* __restrict__ Hb,
                              const float* __restrict__ a_src,
                              const float* __restrict__ a_dst,
                              float* __restrict__ es, float* __restrict__ ed) {
    int i = blockIdx.x * blockDim.x + threadIdx.x;
    if (i >= NN * H) return;
    int n = i / H, h = i % H;
    const int CH = D / H;
    const unsigned short* hp = Hb + (long)n * D + h * CH;
    const float* as = a_src + h * CH;
    const float* ad = a_dst + h * CH;
    float s = 0.f, d = 0.f;
    for (int c = 0; c < CH; c += 8) {
        uint4 u = *(const uint4*)&hp[c];
        float4 a0 = *(const float4*)&as[c];
        float4 a1 = *(const float4*)&as[c + 4];
        float4 b0 = *(const float4*)&ad[c];
        float4 b1 = *(const float4*)&ad[c + 4];
        float f0 = bflo(u.x), f1 = bfhi(u.x), f2 = bflo(u.y), f3 = bfhi(u.y);
        float f4 = bflo(u.z), f5 = bfhi(u.z), f6 = bflo(u.w), f7 = bfhi(u.w);
        s += f0 * a0.x + f1 * a0.y + f2 * a0.z + f3 * a0.w
           + f4 * a1.x + f5 * a1.y + f6 * a1.z + f7 * a1.w;
        d += f0 * b0.x + f1 * b0.y + f2 * b0.z + f3 * b0.w
           + f4 * b1.x + f5 * b1.y + f6 * b1.z + f7 * b1.w;
    }
    es[i] = s; ed[i] = d;
}

// ---------------- aggregation: one wave per dst, wave-cooperative exp ----------------
// lane role A: compute w for edge j = lane/H, head hh = lane&(H-1)   (one exp per lane)
// lane role B: accumulate features fo=lane*2 for its head h = lane>>4 (H=4) / 0 (H=1),
//              pulling w and src via __shfl broadcast.
// RECON: residual recomputed as relu(g*resid + s) from scsh (layer 2)
template <int H, bool RECON>
__global__ __launch_bounds__(256) void agg_kernel(const unsigned short* __restrict__ Hb,
                                                  const float* __restrict__ es,
                                                  const float* __restrict__ ed,
                                                  const int* __restrict__ offs,
                                                  const unsigned short* __restrict__ ssrc,
                                                  const float* __restrict__ bias,
                                                  const float* __restrict__ resid,
                                                  const float* __restrict__ scsh,
                                                  float* __restrict__ out) {
    const int CHK = 64 / H;             // edges per chunk
    int wave = threadIdx.x >> 6;
    int lane = threadIdx.x & 63;
    int dst = blockIdx.x * 4 + wave;
    if (dst >= NN) return;
    int h  = (H == 1) ? 0 : (lane >> 4);        // accumulation head
    int hh = lane & (H - 1);                    // w-computation head
    int fo = lane * 2;
    int beg = offs[dst], end = offs[dst + 1];
    int cnt = end - beg;
    float edv = ed[dst * H + hh];

    float ax0 = 0.f, ay0 = 0.f, ax1 = 0.f, ay1 = 0.f;
    float ds0 = 0.f, ds1 = 0.f;

    for (int base = 0; base < cnt; base += CHK) {
        int j = lane / H;                       // my edge within chunk
        float w = 0.f;
        int msrc = 0;
        if (base + j < cnt) {
            msrc = ssrc[beg + base + j];
            w = __expf(lrelu(es[msrc * H + hh] + edv));
        }
        int lim = min(CHK, cnt - base);
        int jj = 0;
        for (; jj + 1 < lim; jj += 2) {
            float w0 = __shfl(w, jj * H + h);
            float w1 = __shfl(w, (jj + 1) * H + h);
            int s0 = __shfl(msrc, jj * H);
            int s1 = __shfl(msrc, (jj + 1) * H);
            unsigned int u0 = *(const unsigned int*)&Hb[(long)s0 * D + fo];
            unsigned int u1 = *(const unsigned int*)&Hb[(long)s1 * D + fo];
            ax0 += w0 * bflo(u0); ay0 += w0 * bfhi(u0); ds0 += w0;
            ax1 += w1 * bflo(u1); ay1 += w1 * bfhi(u1); ds1 += w1;
        }
        if (jj < lim) {
            float w0 = __shfl(w, jj * H + h);
            int s0 = __shfl(msrc, jj * H);
            unsigned int u0 = *(const unsigned int*)&Hb[(long)s0 * D + fo];
            ax0 += w0 * bflo(u0); ay0 += w0 * bfhi(u0); ds0 += w0;
        }
    }
    float dsum = ds0 + ds1;
    float accx = ax0 + ax1;
    float accy = ay0 + ay1;
    float inv = 1.0f / dsum;
    float2 rr = *(const float2*)&resid[(long)dst * D + fo];
    if (RECON) {
        float2 g = *(const float2*)&scsh[fo];
        float2 s = *(const float2*)&scsh[D + fo];
        rr.x = fmaxf(fmaf(rr.x, g.x, s.x), 0.f);
        rr.y = fmaxf(fmaf(rr.y, g.y, s.y), 0.f);
    }
    float2 o;
    o.x = accx * inv + bias[fo]     + rr.x;
    o.y = accy * inv + bias[fo + 1] + rr.y;
    *(float2*)&out[(long)dst * D + fo] = o;
}

// ---------------- batch-norm stats / finalize / fused apply ----------------
__global__ __launch_bounds__(128) void stats_kernel(const float* __restrict__ y,
                                                    float* __restrict__ st) {
    int f = threadIdx.x;
    float s = 0.f, q = 0.f;
    for (int r = blockIdx.x; r < NN; r += gridDim.x) {
        float v = y[(long)r * D + f];
        s += v; q += v * v;
    }
    atomicAdd(&st[f], s);
    atomicAdd(&st[D + f], q);
}

__global__ void finalize_kernel(const float* __restrict__ st,
                                const float* __restrict__ gamma,
                                const float* __restrict__ beta,
                                float* __restrict__ scsh) {
    int f = threadIdx.x;
    if (f >= D) return;
    float mean = st[f] * (1.0f / NN);
    float var = st[D + f] * (1.0f / NN) - mean * mean;
    float g = gamma[f] * rsqrtf(var + EPSB);
    scsh[f] = g;
    scsh[D + f] = beta[f] - mean * g;
}

template <bool RELU>
__global__ __launch_bounds__(256) void apply_kernel(const float* __restrict__ y,
                                                    const float* __restrict__ st,
                                                    const float* __restrict__ gamma,
                                                    const float* __restrict__ beta,
                                                    float* __restrict__ out) {
    long i = (long)(blockIdx.x * blockDim.x + threadIdx.x) * 4;
    if (i >= (long)NN * D) return;
    int f = (int)(i & (D - 1));
    const float invn = 1.0f / NN;
    float4 sv = *(const float4*)&st[f];
    float4 qv = *(const float4*)&st[D + f];
    float4 gv = *(const float4*)&gamma[f];
    float4 bv = *(const float4*)&beta[f];
    float4 v = *(const float4*)&y[i];
    float4 o;
    float m, vr, g;
    m = sv.x * invn; vr = qv.x * invn - m * m; g = gv.x * rsqrtf(vr + EPSB);
    o.x = (v.x - m) * g + bv.x;
    m = sv.y * invn; vr = qv.y * invn - m * m; g = gv.y * rsqrtf(vr + EPSB);
    o.y = (v.y - m) * g + bv.y;
    m = sv.z * invn; vr = qv.z * invn - m * m; g = gv.z * rsqrtf(vr + EPSB);
    o.z = (v.z - m) * g + bv.z;
    m = sv.w * invn; vr = qv.w * invn - m * m; g = gv.w * rsqrtf(vr + EPSB);
    o.w = (v.w - m) * g + bv.w;
    if (RELU) {
        o.x = fmaxf(o.x, 0.f); o.y = fmaxf(o.y, 0.f);
        o.z = fmaxf(o.z, 0.f); o.w = fmaxf(o.w, 0.f);
    }
    *(float4*)&out[i] = o;
}

extern "C" void kernel_launch(void* const* d_in, const int* in_sizes, int n_in,
                              void* d_out, int out_size, void* d_ws, size_t ws_size,
                              hipStream_t stream) {
    const float* x      = (const float*)d_in[0];
    const int*   ei     = (const int*)  d_in[1];
    const float* W1     = (const float*)d_in[2];
    const float* a_src1 = (const float*)d_in[3];
    const float* a_dst1 = (const float*)d_in[4];
    const float* b1     = (const float*)d_in[5];
    const float* W2     = (const float*)d_in[6];
    const float* a_src2 = (const float*)d_in[7];
    const float* a_dst2 = (const float*)d_in[8];
    const float* b2     = (const float*)d_in[9];
    const float* gamma  = (const float*)d_in[10];
    const float* beta   = (const float*)d_in[11];
    float* out = (float*)d_out;

    // workspace layout
    unsigned short* Hb = (unsigned short*)d_ws;          // 6.4M bf16 (12.8 MB)
    float* B    = (float*)d_ws + 3200000;                // y1 = h1+res (pre-BN)
    float* es1  = B + 6400000;                           // 200000 ([NN][4])
    float* ed1  = es1 + 200000;
    float* es2  = ed1 + 200000;                          // 50000
    float* ed2  = es2 + 50000;
    float* st1  = ed2 + 50000;                           // 256
    float* st2  = st1 + 256;
    float* scsh1= st2 + 256;                             // 256
    int*   deg  = (int*)(scsh1 + 256);                   // NN
    int*   offs = deg + NN;                              // NN+1
    int*   cur  = offs + NN + 1;                         // NN
    int*   tmp  = cur + NN;                              // NN
    int*   bsum = tmp + NN;                              // SCB
    unsigned short* ssrc = (unsigned short*)(bsum + SCB + 4);  // ET ushort
    unsigned short* wt1  = ssrc + ((ET + 7) & ~7);
    unsigned short* wt2  = wt1 + D * D;

    hipMemsetAsync(deg, 0, NN * sizeof(int), stream);
    hipMemsetAsync(st1, 0, 512 * sizeof(float), stream);

    wconv_kernel<<<(2 * D * D + 255) / 256, 256, 0, stream>>>(W1, W2, wt1, wt2);
    hist_kernel<<<(ET + 255) / 256, 256, 0, stream>>>(ei, deg);
    scan_a_kernel<<<SCB, 256, 0, stream>>>(deg, tmp, bsum);
    scan_b_kernel<<<SCB, 256, 0, stream>>>(deg, tmp, bsum, offs, cur);
    scatter_kernel<<<(ET + 255) / 256, 256, 0, stream>>>(ei, cur, ssrc);

    const int GG = (NN + 63) / 64;
    // ---- layer 1 ----
    gemm_mfma_kernel<false><<<GG, 256, 0, stream>>>(x, wt1, nullptr, Hb, NN);
    logits_kernel<4><<<(NN * 4 + 255) / 256, 256, 0, stream>>>(Hb, a_src1, a_dst1, es1, ed1);
    agg_kernel<4, false><<<(NN + 3) / 4, 256, 0, stream>>>(Hb, es1, ed1, offs, ssrc, b1, x, nullptr, B);
    stats_kernel<<<1024, 128, 0, stream>>>(B, st1);
    finalize_kernel<<<1, 128, 0, stream>>>(st1, gamma, beta, scsh1);

    // ---- layer 2 (BN+ReLU of layer1 fused into staging / residual recompute) ----
    gemm_mfma_kernel<true><<<GG, 256, 0, stream>>>(B, wt2, scsh1, Hb, NN);
    logits_kernel<1><<<(NN + 255) / 256, 256, 0, stream>>>(Hb, a_src2, a_dst2, es2, ed2);
    agg_kernel<1, true><<<(NN + 3) / 4, 256, 0, stream>>>(Hb, es2, ed2, offs, ssrc, b2, B, scsh1, out);
    stats_kernel<<<1024, 128, 0, stream>>>(out, st2);
    apply_kernel<false><<<(NN * D / 4 + 255) / 256, 256, 0, stream>>>(out, st2, gamma, beta, out);
}

// Round 11
// 357.009 us; speedup vs baseline: 1.0741x; 1.0358x over previous
//
#include <hip/hip_runtime.h>
#include <math.h>

#define NN 50000
#define NE 600000
#define ET (NE + NN)        // 650000 edges incl self loops
#define D 128
#define EPSB 1e-5f
#define SLOPE 0.2f
#define XPITCH 136          // LDS row pitch in bf16 elems (128 + 8 pad)
#define SCB 196             // scan blocks: 196*256 = 50176 >= NN

typedef float f32x4 __attribute__((ext_vector_type(4)));
typedef short bf16x8 __attribute__((ext_vector_type(8)));

__device__ inline unsigned short bf16r(float f) {           // f32 -> bf16 RNE
    unsigned int u = __float_as_uint(f);
    unsigned int r = (u + 0x7fff + ((u >> 16) & 1)) >> 16;
    return (unsigned short)r;
}
__device__ inline float bflo(unsigned int u) { return __uint_as_float(u << 16); }
__device__ inline float bfhi(unsigned int u) { return __uint_as_float(u & 0xffff0000u); }
__device__ inline float b2f(unsigned short u) { return __uint_as_float(((unsigned int)u) << 16); }
__device__ inline float lrelu(float e) { return (e > 0.f) ? e : SLOPE * e; }

// ---------------- setup: zero deg/st, convert both W -> bf16 transposed ----------------
__global__ __launch_bounds__(256) void setup_kernel(const float* __restrict__ W1,
                                                    const float* __restrict__ W2,
                                                    unsigned short* __restrict__ wt1,
                                                    unsigned short* __restrict__ wt2,
                                                    int* __restrict__ deg,
                                                    float* __restrict__ stz) {
    int t = blockIdx.x * blockDim.x + threadIdx.x;
    if (t < NN) deg[t] = 0;
    if (t < 512) stz[t] = 0.f;
    if (t < D * D) {
        int n = t >> 7, k = t & 127;
        wt1[t] = bf16r(W1[k * D + n]);
    } else if (t < 2 * D * D) {
        int i = t - D * D;
        int n = i >> 7, k = i & 127;
        wt2[i] = bf16r(W2[k * D + n]);
    }
}

// ---------------- CSR build ----------------
__global__ void hist_kernel(const int* __restrict__ ei, int* __restrict__ deg) {
    int e = blockIdx.x * blockDim.x + threadIdx.x;
    if (e >= ET) return;
    int dst = (e < NE) ? ei[NE + e] : (e - NE);
    atomicAdd(&deg[dst], 1);
}

__global__ __launch_bounds__(256) void scan_a_kernel(const int* __restrict__ deg,
                                                     int* __restrict__ tmp,
                                                     int* __restrict__ bsum) {
    __shared__ int sm[256];
    int t = threadIdx.x;
    int idx = blockIdx.x * 256 + t;
    int v = (idx < NN) ? deg[idx] : 0;
    sm[t] = v;
    __syncthreads();
    #pragma unroll
    for (int d = 1; d < 256; d <<= 1) {
        int add = (t >= d) ? sm[t - d] : 0;
        __syncthreads();
        sm[t] += add;
        __syncthreads();
    }
    if (idx < NN) tmp[idx] = sm[t];
    if (t == 255) bsum[blockIdx.x] = sm[255];
}

__global__ __launch_bounds__(256) void scan_b_kernel(const int* __restrict__ deg,
                                                     const int* __restrict__ tmp,
                                                     const int* __restrict__ bsum,
                                                     int* __restrict__ offs,
                                                     int* __restrict__ cur) {
    __shared__ int sm[256];
    int t = threadIdx.x;
    sm[t] = (t < SCB) ? bsum[t] : 0;
    __syncthreads();
    #pragma unroll
    for (int d = 1; d < 256; d <<= 1) {
        int add = (t >= d) ? sm[t - d] : 0;
        __syncthreads();
        sm[t] += add;
        __syncthreads();
    }
    int bpre = (blockIdx.x == 0) ? 0 : sm[blockIdx.x - 1];
    int idx = blockIdx.x * 256 + t;
    if (idx < NN) {
        int excl = bpre + tmp[idx] - deg[idx];
        offs[idx] = excl;
        cur[idx] = excl;
        if (idx == NN - 1) offs[NN] = bpre + tmp[idx];   // == ET
    }
}

__global__ void scatter_kernel(const int* __restrict__ ei, int* __restrict__ cur,
                               unsigned short* __restrict__ ssrc) {
    int e = blockIdx.x * blockDim.x + threadIdx.x;
    if (e >= ET) return;
    int src, dst;
    if (e < NE) { src = ei[e]; dst = ei[NE + e]; }
    else        { src = dst = e - NE; }
    int pos = atomicAdd(&cur[dst], 1);
    ssrc[pos] = (unsigned short)src;
}

// ---------------- MFMA GEMM + fused logits ----------------
// Hb(bf16) = f(X) @ W ; f = BN+ReLU (from raw sums st) if BNRELU (X is then bf16)
// es/ed computed in-block from the C tile staged in LDS (reusing Xl space).
template <int H, bool BNRELU>
__global__ __launch_bounds__(256) void gemm_mfma_kernel(
        const float* __restrict__ Xf, const unsigned short* __restrict__ Xb,
        const unsigned short* __restrict__ Wt,
        const float* __restrict__ st, const float* __restrict__ gamma,
        const float* __restrict__ beta,
        const float* __restrict__ a_src, const float* __restrict__ a_dst,
        unsigned short* __restrict__ Hb, float* __restrict__ es, float* __restrict__ ed,
        int nrows) {
    __shared__ unsigned short Xl[64 * XPITCH];     // X tile, later reused as C tile
    __shared__ unsigned short Wl[128 * XPITCH];
    __shared__ float scshl[256];
    int t = threadIdx.x;
    int row0 = blockIdx.x * 64;

    if (BNRELU && t < 128) {
        float mean = st[t] * (1.0f / NN);
        float var = st[128 + t] * (1.0f / NN) - mean * mean;
        float g = gamma[t] * rsqrtf(var + EPSB);
        scshl[t] = g;
        scshl[128 + t] = beta[t] - mean * g;
    }
    // stage W (bf16 transposed [n][k])
    {
        int r = t >> 1, cb = (t & 1) * 64;
        const uint4* src = (const uint4*)&Wt[r * D + cb];
        uint4* dst = (uint4*)&Wl[r * XPITCH + cb];
        #pragma unroll
        for (int j = 0; j < 8; ++j) dst[j] = src[j];
    }
    if (BNRELU) __syncthreads();            // scshl ready before X staging uses it
    // stage X
    {
        int r = t >> 2, cb = (t & 3) * 32;
        int gr = row0 + r; if (gr >= nrows) gr = nrows - 1;
        if (!BNRELU) {
            const float4* src = (const float4*)&Xf[(long)gr * D + cb];
            #pragma unroll
            for (int j = 0; j < 8; ++j) {
                float4 v = src[j];
                ushort4 p;
                p.x = bf16r(v.x); p.y = bf16r(v.y);
                p.z = bf16r(v.z); p.w = bf16r(v.w);
                *(ushort4*)&Xl[r * XPITCH + cb + j * 4] = p;
            }
        } else {
            #pragma unroll
            for (int j = 0; j < 4; ++j) {           // 8 bf16 per iter
                uint4 u = *(const uint4*)&Xb[(long)gr * D + cb + j * 8];
                unsigned int uu0 = u.x, uu1 = u.y, uu2 = u.z, uu3 = u.w;
                ushort4 p0, p1;
                int fb = cb + j * 8;
                p0.x = bf16r(fmaxf(fmaf(bflo(uu0), scshl[fb+0], scshl[128+fb+0]), 0.f));
                p0.y = bf16r(fmaxf(fmaf(bfhi(uu0), scshl[fb+1], scshl[128+fb+1]), 0.f));
                p0.z = bf16r(fmaxf(fmaf(bflo(uu1), scshl[fb+2], scshl[128+fb+2]), 0.f));
                p0.w = bf16r(fmaxf(fmaf(bfhi(uu1), scshl[fb+3], scshl[128+fb+3]), 0.f));
                p1.x = bf16r(fmaxf(fmaf(bflo(uu2), scshl[fb+4], scshl[128+fb+4]), 0.f));
                p1.y = bf16r(fmaxf(fmaf(bfhi(uu2), scshl[fb+5], scshl[128+fb+5]), 0.f));
                p1.z = bf16r(fmaxf(fmaf(bflo(uu3), scshl[fb+6], scshl[128+fb+6]), 0.f));
                p1.w = bf16r(fmaxf(fmaf(bfhi(uu3), scshl[fb+7], scshl[128+fb+7]), 0.f));
                *(ushort4*)&Xl[r * XPITCH + fb] = p0;
                *(ushort4*)&Xl[r * XPITCH + fb + 4] = p1;
            }
        }
    }
    __syncthreads();

    int wv = t >> 6, l = t & 63;
    int lr = l & 15, lg = l >> 4;
    f32x4 acc[8];
    #pragma unroll
    for (int n = 0; n < 8; ++n) acc[n] = (f32x4){0.f, 0.f, 0.f, 0.f};

    #pragma unroll
    for (int kc = 0; kc < 4; ++kc) {
        bf16x8 a = *(const bf16x8*)&Xl[(wv * 16 + lr) * XPITCH + kc * 32 + lg * 8];
        #pragma unroll
        for (int n = 0; n < 8; ++n) {
            bf16x8 b = *(const bf16x8*)&Wl[(n * 16 + lr) * XPITCH + kc * 32 + lg * 8];
            acc[n] = __builtin_amdgcn_mfma_f32_16x16x32_bf16(a, b, acc[n], 0, 0, 0);
        }
    }
    __syncthreads();                        // all waves done reading Xl
    // epilogue: write Hb global + C tile into Xl space (wave-local rows)
    int trow0 = wv * 16 + lg * 4;
    int growb = row0 + trow0;
    #pragma unroll
    for (int n = 0; n < 8; ++n) {
        #pragma unroll
        for (int j = 0; j < 4; ++j) {
            unsigned short us = bf16r(acc[n][j]);
            Xl[(trow0 + j) * XPITCH + n * 16 + lr] = us;
            int gr = growb + j;
            if (gr < nrows) Hb[(long)gr * D + n * 16 + lr] = us;
        }
    }
    __syncthreads();
    // fused logits: wave wv handles tile rows wv*16..+15; lane = rl*4+q, q = 32-col chunk
    {
        int rl = l >> 2, q = l & 3;
        int trow = wv * 16 + rl;
        int gr = row0 + trow;
        const unsigned short* cp = &Xl[trow * XPITCH + q * 32];
        const float* as = a_src + q * 32;   // H=4: head q; H=1: cols q*32..
        const float* ad = a_dst + q * 32;
        float s = 0.f, d2 = 0.f;
        #pragma unroll
        for (int c = 0; c < 32; c += 8) {
            uint4 u = *(const uint4*)&cp[c];
            float4 a0 = *(const float4*)&as[c];
            float4 a1 = *(const float4*)&as[c + 4];
            float4 b0 = *(const float4*)&ad[c];
            float4 b1 = *(const float4*)&ad[c + 4];
            float f0 = bflo(u.x), f1 = bfhi(u.x), f2 = bflo(u.y), f3 = bfhi(u.y);
            float f4 = bflo(u.z), f5 = bfhi(u.z), f6 = bflo(u.w), f7 = bfhi(u.w);
            s  += f0*a0.x + f1*a0.y + f2*a0.z + f3*a0.w
                + f4*a1.x + f5*a1.y + f6*a1.z + f7*a1.w;
            d2 += f0*b0.x + f1*b0.y + f2*b0.z + f3*b0.w
                + f4*b1.x + f5*b1.y + f6*b1.z + f7*b1.w;
        }
        if (H == 4) {
            if (gr < nrows) { es[gr * 4 + q] = s; ed[gr * 4 + q] = d2; }
        } else {
            s  += __shfl_xor(s, 1);  s  += __shfl_xor(s, 2);
            d2 += __shfl_xor(d2, 1); d2 += __shfl_xor(d2, 2);
            if (q == 0 && gr < nrows) { es[gr] = s; ed[gr] = d2; }
        }
    }
}

// ---------------- aggregation: one wave per dst, wave-cooperative exp ----------------
template <int H, bool RECON, bool OUTBF16>
__global__ __launch_bounds__(256) void agg_kernel(
        const unsigned short* __restrict__ Hb,
        const float* __restrict__ es, const float* __restrict__ ed,
        const int* __restrict__ offs, const unsigned short* __restrict__ ssrc,
        const float* __restrict__ bias,
        const float* __restrict__ residf, const unsigned short* __restrict__ residb,
        const float* __restrict__ st, const float* __restrict__ gamma,
        const float* __restrict__ beta,
        float* __restrict__ outf, unsigned short* __restrict__ outb) {
    const int CHK = 64 / H;             // edges per chunk
    int wave = threadIdx.x >> 6;
    int lane = threadIdx.x & 63;
    int dst = blockIdx.x * 4 + wave;
    if (dst >= NN) return;
    int h  = (H == 1) ? 0 : (lane >> 4);        // accumulation head
    int hh = lane & (H - 1);                    // w-computation head
    int fo = lane * 2;
    int beg = offs[dst], end = offs[dst + 1];
    int cnt = end - beg;
    float edv = ed[dst * H + hh];

    float ax0 = 0.f, ay0 = 0.f, ax1 = 0.f, ay1 = 0.f;
    float ds0 = 0.f, ds1 = 0.f;

    for (int base = 0; base < cnt; base += CHK) {
        int j = lane / H;                       // my edge within chunk
        float w = 0.f;
        int msrc = 0;
        if (base + j < cnt) {
            msrc = ssrc[beg + base + j];
            w = __expf(lrelu(es[msrc * H + hh] + edv));
        }
        int lim = min(CHK, cnt - base);
        int jj = 0;
        for (; jj + 1 < lim; jj += 2) {
            float w0 = __shfl(w, jj * H + h);
            float w1 = __shfl(w, (jj + 1) * H + h);
            int s0 = __shfl(msrc, jj * H);
            int s1 = __shfl(msrc, (jj + 1) * H);
            unsigned int u0 = *(const unsigned int*)&Hb[(long)s0 * D + fo];
            unsigned int u1 = *(const unsigned int*)&Hb[(long)s1 * D + fo];
            ax0 += w0 * bflo(u0); ay0 += w0 * bfhi(u0); ds0 += w0;
            ax1 += w1 * bflo(u1); ay1 += w1 * bfhi(u1); ds1 += w1;
        }
        if (jj < lim) {
            float w0 = __shfl(w, jj * H + h);
            int s0 = __shfl(msrc, jj * H);
            unsigned int u0 = *(const unsigned int*)&Hb[(long)s0 * D + fo];
            ax0 += w0 * bflo(u0); ay0 += w0 * bfhi(u0); ds0 += w0;
        }
    }
    float dsum = ds0 + ds1;
    float accx = ax0 + ax1;
    float accy = ay0 + ay1;
    float inv = 1.0f / dsum;
    float rx, ry;
    if (RECON) {
        unsigned int ur = *(const unsigned int*)&residb[(long)dst * D + fo];
        float y0 = bflo(ur), y1 = bfhi(ur);
        float m0 = st[fo] * (1.0f / NN);
        float v0 = st[128 + fo] * (1.0f / NN) - m0 * m0;
        float g0 = gamma[fo] * rsqrtf(v0 + EPSB);
        float s0v = beta[fo] - m0 * g0;
        float m1 = st[fo + 1] * (1.0f / NN);
        float v1 = st[128 + fo + 1] * (1.0f / NN) - m1 * m1;
        float g1 = gamma[fo + 1] * rsqrtf(v1 + EPSB);
        float s1v = beta[fo + 1] - m1 * g1;
        rx = fmaxf(fmaf(y0, g0, s0v), 0.f);
        ry = fmaxf(fmaf(y1, g1, s1v), 0.f);
    } else {
        float2 r2 = *(const float2*)&residf[(long)dst * D + fo];
        rx = r2.x; ry = r2.y;
    }
    float ox = accx * inv + bias[fo]     + rx;
    float oy = accy * inv + bias[fo + 1] + ry;
    if (OUTBF16) {
        unsigned int pk = (unsigned int)bf16r(ox) | ((unsigned int)bf16r(oy) << 16);
        *(unsigned int*)&outb[(long)dst * D + fo] = pk;
    } else {
        float2 o; o.x = ox; o.y = oy;
        *(float2*)&outf[(long)dst * D + fo] = o;
    }
}

// ---------------- batch-norm stats (f32 or bf16 input) ----------------
template <bool BF16IN>
__global__ __launch_bounds__(128) void stats_kernel(const float* __restrict__ yf,
                                                    const unsigned short* __restrict__ yb,
                                                    float* __restrict__ st) {
    int f = threadIdx.x;
    float s = 0.f, q = 0.f;
    for (int r = blockIdx.x; r < NN; r += gridDim.x) {
        float v = BF16IN ? b2f(yb[(long)r * D + f]) : yf[(long)r * D + f];
        s += v; q += v * v;
    }
    atomicAdd(&st[f], s);
    atomicAdd(&st[D + f], q);
}

// ---------------- final BN apply (finalize fused, per-element) ----------------
__global__ __launch_bounds__(256) void apply_kernel(const float* __restrict__ y,
                                                    const float* __restrict__ st,
                                                    const float* __restrict__ gamma,
                                                    const float* __restrict__ beta,
                                                    float* __restrict__ out) {
    long i = (long)(blockIdx.x * blockDim.x + threadIdx.x) * 4;
    if (i >= (long)NN * D) return;
    int f = (int)(i & (D - 1));
    const float invn = 1.0f / NN;
    float4 sv = *(const float4*)&st[f];
    float4 qv = *(const float4*)&st[D + f];
    float4 gv = *(const float4*)&gamma[f];
    float4 bv = *(const float4*)&beta[f];
    float4 v = *(const float4*)&y[i];
    float4 o;
    float m, vr, g;
    m = sv.x * invn; vr = qv.x * invn - m * m; g = gv.x * rsqrtf(vr + EPSB);
    o.x = (v.x - m) * g + bv.x;
    m = sv.y * invn; vr = qv.y * invn - m * m; g = gv.y * rsqrtf(vr + EPSB);
    o.y = (v.y - m) * g + bv.y;
    m = sv.z * invn; vr = qv.z * invn - m * m; g = gv.z * rsqrtf(vr + EPSB);
    o.z = (v.z - m) * g + bv.z;
    m = sv.w * invn; vr = qv.w * invn - m * m; g = gv.w * rsqrtf(vr + EPSB);
    o.w = (v.w - m) * g + bv.w;
    *(float4*)&out[i] = o;
}

extern "C" void kernel_launch(void* const* d_in, const int* in_sizes, int n_in,
                              void* d_out, int out_size, void* d_ws, size_t ws_size,
                              hipStream_t stream) {
    const float* x      = (const float*)d_in[0];
    const int*   ei     = (const int*)  d_in[1];
    const float* W1     = (const float*)d_in[2];
    const float* a_src1 = (const float*)d_in[3];
    const float* a_dst1 = (const float*)d_in[4];
    const float* b1     = (const float*)d_in[5];
    const float* W2     = (const float*)d_in[6];
    const float* a_src2 = (const float*)d_in[7];
    const float* a_dst2 = (const float*)d_in[8];
    const float* b2     = (const float*)d_in[9];
    const float* gamma  = (const float*)d_in[10];
    const float* beta   = (const float*)d_in[11];
    float* out = (float*)d_out;

    // workspace layout (16B-aligned sections)
    unsigned short* Hb = (unsigned short*)d_ws;          // 6.4M bf16
    unsigned short* Bb = Hb + 6400000;                   // 6.4M bf16 (y1)
    float* es1  = (float*)(Bb + 6400000);                // [NN][4]
    float* ed1  = es1 + 200000;
    float* es2  = ed1 + 200000;                          // [NN]
    float* ed2  = es2 + 50000;
    float* st1  = ed2 + 50000;                           // 256
    float* st2  = st1 + 256;                             // 256 (contiguous zero)
    unsigned short* wt1 = (unsigned short*)(st2 + 256);  // D*D bf16
    unsigned short* wt2 = wt1 + D * D;
    int*   deg  = (int*)(wt2 + D * D);                   // NN
    int*   offs = deg + NN;                              // NN+1
    int*   cur  = offs + NN + 1;                         // NN
    int*   tmp  = cur + NN;                              // NN
    int*   bsum = tmp + NN;                              // SCB
    unsigned short* ssrc = (unsigned short*)(bsum + SCB + 4);  // ET ushort

    setup_kernel<<<SCB, 256, 0, stream>>>(W1, W2, wt1, wt2, deg, st1);
    hist_kernel<<<(ET + 255) / 256, 256, 0, stream>>>(ei, deg);
    scan_a_kernel<<<SCB, 256, 0, stream>>>(deg, tmp, bsum);
    scan_b_kernel<<<SCB, 256, 0, stream>>>(deg, tmp, bsum, offs, cur);
    scatter_kernel<<<(ET + 255) / 256, 256, 0, stream>>>(ei, cur, ssrc);

    const int GG = (NN + 63) / 64;
    // ---- layer 1 ----
    gemm_mfma_kernel<4, false><<<GG, 256, 0, stream>>>(
        x, nullptr, wt1, nullptr, nullptr, nullptr, a_src1, a_dst1, Hb, es1, ed1, NN);
    agg_kernel<4, false, true><<<(NN + 3) / 4, 256, 0, stream>>>(
        Hb, es1, ed1, offs, ssrc, b1, x, nullptr, nullptr, nullptr, nullptr, nullptr, Bb);
    stats_kernel<true><<<1024, 128, 0, stream>>>(nullptr, Bb, st1);

    // ---- layer 2 (BN+ReLU fused into staging / residual recompute) ----
    gemm_mfma_kernel<1, true><<<GG, 256, 0, stream>>>(
        nullptr, Bb, wt2, st1, gamma, beta, a_src2, a_dst2, Hb, es2, ed2, NN);
    agg_kernel<1, true, false><<<(NN + 3) / 4, 256, 0, stream>>>(
        Hb, es2, ed2, offs, ssrc, b2, nullptr, Bb, st1, gamma, beta, out, nullptr);
    stats_kernel<false><<<1024, 128, 0, stream>>>(out, nullptr, st2);
    apply_kernel<<<(NN * D / 4 + 255) / 256, 256, 0, stream>>>(out, st2, gamma, beta, out);
}